// Round 5
// baseline (165.449 us; speedup 1.0000x reference)
//
#include <hip/hip_runtime.h>
#include <hip/hip_bf16.h>
#include <cstdint>
#include <cstddef>
#include <math.h>

#define B_SZ 512
#define E_SZ 512
#define C_SZ 70722
#define BN 64
#define NBLK 1106            // ceil(70722/64)
#define M_MARGIN 0.4f
#define H_CONST 0.333f
#define S_CONST 64.0f
#define EPS_F 1e-3f
#define PI_F 3.14159265358979323846f

typedef __attribute__((ext_vector_type(8))) short short8;
typedef __attribute__((ext_vector_type(4))) float f32x4;

// ---------------- helpers ----------------

__device__ __forceinline__ unsigned short f2bf(float x) {
  __hip_bfloat16 h = __float2bfloat16(x);
  unsigned short u;
  __builtin_memcpy(&u, &h, 2);
  return u;
}

__device__ __forceinline__ void gload_lds16(const void* g, void* l) {
  __builtin_amdgcn_global_load_lds(
      (const __attribute__((address_space(1))) unsigned int*)g,
      (__attribute__((address_space(3))) unsigned int*)l, 16, 0, 0);
}

// 4x4 transpose across lane groups {l, l^16, l^32, l^48} (R4-verified).
// Lanes q=0..3 (bits 4-5) hold rows q; output y[j] = row j's component q.
__device__ __forceinline__ f32x4 xpose4(float4 v, int lane) {
  bool h32 = (lane & 32) != 0;
  float t2 = h32 ? v.x : v.z;
  float t3 = h32 ? v.y : v.w;
  float x2 = __shfl_xor(t2, 32);
  float x3 = __shfl_xor(t3, 32);
  float u0 = h32 ? x2 : v.x;
  float u1 = h32 ? x3 : v.y;
  float u2 = h32 ? v.z : x2;
  float u3 = h32 ? v.w : x3;
  bool h16 = (lane & 16) != 0;
  float s0 = h16 ? u0 : u1;
  float s1 = h16 ? u2 : u3;
  float z0 = __shfl_xor(s0, 16);
  float z1 = __shfl_xor(s1, 16);
  f32x4 y;
  y[0] = h16 ? z0 : u0;
  y[1] = h16 ? u1 : z0;
  y[2] = h16 ? z1 : u2;
  y[3] = h16 ? u3 : z1;
  return y;
}

// ---------------- kernel 1: per-row margin stats ----------------
__global__ void k_stats(const float* __restrict__ norms, const int* __restrict__ label,
                        float* __restrict__ ga, float* __restrict__ gadd) {
  __shared__ float sn[B_SZ];
  __shared__ int lab[B_SZ];
  __shared__ float redA[8], redB[8];
  __shared__ float sh_std;

  int t = threadIdx.x;
  float v = norms[t];
  v = fminf(fmaxf(v, 1e-3f), 100.0f);
  sn[t] = v;
  lab[t] = label[t];

  float s1 = v, s2 = v * v;
  #pragma unroll
  for (int o = 32; o > 0; o >>= 1) {
    s1 += __shfl_down(s1, o);
    s2 += __shfl_down(s2, o);
  }
  if ((t & 63) == 0) { redA[t >> 6] = s1; redB[t >> 6] = s2; }
  __syncthreads();
  if (t == 0) {
    float a = 0.f, b = 0.f;
    #pragma unroll
    for (int i = 0; i < 8; ++i) { a += redA[i]; b += redB[i]; }
    float mean = a / (float)B_SZ;
    float var = (b - (float)B_SZ * mean * mean) / (float)(B_SZ - 1);
    sh_std = sqrtf(fmaxf(var, 0.f));
  }
  __syncthreads();
  float stdv = sh_std;

  int myl = lab[t];
  float s = 0.f, cnt = 0.f;
  for (int j = 0; j < B_SZ; ++j) {
    bool m = (lab[j] == myl);
    s += m ? sn[j] : 0.f;
    cnt += m ? 1.f : 0.f;
  }
  float gm = s / fmaxf(cnt, 1.f);
  float ms = (v - gm) / (stdv + EPS_F) * H_CONST;
  ms = fminf(fmaxf(ms, -1.f), 1.f);
  ga[t] = -M_MARGIN * ms;
  gadd[t] = M_MARGIN + M_MARGIN * ms;
}

// ---------------- kernel 2: emb fp32 -> bf16 ----------------
__global__ void k_cvtA(const float* __restrict__ emb, unsigned short* __restrict__ abf) {
  int i = (blockIdx.x * 256 + threadIdx.x) * 4;
  float4 f = *(const float4*)(emb + i);
  unsigned short u0 = f2bf(f.x), u1 = f2bf(f.y), u2 = f2bf(f.z), u3 = f2bf(f.w);
  unsigned long long pk = (unsigned long long)u0 | ((unsigned long long)u1 << 16) |
                          ((unsigned long long)u2 << 32) | ((unsigned long long)u3 << 48);
  *(unsigned long long*)(abf + i) = pk;
}

// ---------------- kernel 3: fused GEMM + colnorm + epilogue ----------------
// Block: M=512 x N=64, K=512, BK=64 (8 steps). 512 thr = 8 waves; wave w owns
// rows w*64..w*64+63 (wave-private As region -> no cross-wave A hazard).
// As[512][64bf16] (128B rows, swzb), staged via global_load_lds (pre-swizzled src).
// B: fp32 coalesced loads 2-step-deep in regs -> 2x 4x4 shfl transpose -> bf16
// pack -> ds_write_b128 into Bs[2][64][64bf16] (swzb; uniform bank coverage).
// Column sumsq accumulated post-transpose (lane owns one col); invn in-block.
__launch_bounds__(512, 2)
__global__ void k_gemm_full(const unsigned short* __restrict__ Abf,  // [512][512] bf16
                            const float* __restrict__ Kmat,          // [512][C]
                            const int* __restrict__ label,
                            const float* __restrict__ ga,
                            const float* __restrict__ gadd,
                            float* __restrict__ out) {
  __shared__ __align__(16) unsigned short As[512 * 64];    // 64 KB
  __shared__ __align__(16) unsigned short Bs[2][64 * 64];  // 2 x 8 KB
  __shared__ float red[8][64];
  __shared__ float invn_s[64];
  __shared__ int lab_s[512];
  __shared__ float ga_s[512], gadd_s[512];

  const int tid = threadIdx.x;
  const int w = tid >> 6;
  const int lane = tid & 63;
  const int q = lane >> 4;            // 0..3
  const int l15 = lane & 15;
  const int c0 = blockIdx.x * BN;
  const bool edge = (c0 + BN > C_SZ);

  lab_s[tid] = label[tid];
  ga_s[tid] = ga[tid];
  gadd_s[tid] = gadd[tid];

  // ---- A staging: wave w stages rows w*64..+63, 8 x gload_lds (8 rows each) ----
  const int ar = lane >> 3;           // 0..7
  const int ac = lane & 7;            // source 16B chunk (pre-swizzled)
  char* const adst = (char*)As + (w * 64) * 128;

  // ---- B load: rows w*8 + q*2 + {0,1}, cols c0 + l15*4 .. +3 ----
  const float* const bsrc = Kmat + (size_t)(w * 8 + q * 2) * C_SZ + c0 + l15 * 4;
  // ---- B write: col cT = l15*4+q, k-chunk w, swizzled ----
  const int cT = l15 * 4 + q;
  const int swzT = (cT & 7) ^ ((cT >> 2) & 7);
  char* const bdst = (char*)&Bs[0][0] + cT * 128 + ((w ^ swzT) << 4);

  // ---- fragment LDS byte offsets (ks=0; ks=1 = ^64) ----
  int offA[4], offB[4];
  #pragma unroll
  for (int m = 0; m < 4; ++m) {
    int row = w * 64 + m * 16 + l15;
    int swz = (row & 7) ^ ((row >> 2) & 7);
    offA[m] = row * 128 + ((q ^ swz) << 4);
  }
  #pragma unroll
  for (int n = 0; n < 4; ++n) {
    int c = n * 16 + l15;
    int swz = (c & 7) ^ ((c >> 2) & 7);
    offB[n] = c * 128 + ((q ^ swz) << 4);
  }

  f32x4 acc[4][4];
  #pragma unroll
  for (int m = 0; m < 4; ++m)
    #pragma unroll
    for (int n = 0; n < 4; ++n)
      acc[m][n] = f32x4{0.f, 0.f, 0.f, 0.f};

  float ss = 0.f;          // sumsq of column cT (post-transpose, lane-owned)
  float4 bv[2][2];         // 2-step-deep raw B (static indices after unroll)

#define ASTAGE(KB)                                                          \
  {                                                                         \
    _Pragma("unroll")                                                       \
    for (int rr = 0; rr < 8; ++rr) {                                        \
      int r = w * 64 + rr * 8 + ar;                                         \
      int s = ac ^ ((r & 7) ^ ((r >> 2) & 7));                              \
      gload_lds16(Abf + (size_t)r * 512 + (KB) + s * 8, adst + rr * 1024);  \
    }                                                                       \
  }

#define BLOADP(SLOT, KB)                                                    \
  {                                                                         \
    const float* s0 = bsrc + (size_t)(KB) * C_SZ;                           \
    if (!edge) {                                                            \
      bv[SLOT][0] = *(const float4*)s0;                                     \
      bv[SLOT][1] = *(const float4*)(s0 + C_SZ);                            \
    } else {                                                                \
      float* p0 = (float*)&bv[SLOT][0];                                     \
      float* p1 = (float*)&bv[SLOT][1];                                     \
      _Pragma("unroll")                                                     \
      for (int j = 0; j < 4; ++j) {                                         \
        bool ok = (c0 + l15 * 4 + j) < C_SZ;                                \
        p0[j] = ok ? s0[j] : 0.f;                                           \
        p1[j] = ok ? s0[(size_t)C_SZ + j] : 0.f;                            \
      }                                                                     \
    }                                                                       \
  }

#define XW(SLOT, BUF)                                                       \
  {                                                                         \
    f32x4 te = xpose4(bv[SLOT][0], lane);  /* k = w*8 + {0,2,4,6} */        \
    f32x4 to = xpose4(bv[SLOT][1], lane);  /* k = w*8 + {1,3,5,7} */        \
    ss += te[0] * te[0] + to[0] * to[0];                                    \
    ss += te[1] * te[1] + to[1] * to[1];                                    \
    ss += te[2] * te[2] + to[2] * to[2];                                    \
    ss += te[3] * te[3] + to[3] * to[3];                                    \
    uint4 pk;                                                               \
    pk.x = (unsigned)f2bf(te[0]) | ((unsigned)f2bf(to[0]) << 16);           \
    pk.y = (unsigned)f2bf(te[1]) | ((unsigned)f2bf(to[1]) << 16);           \
    pk.z = (unsigned)f2bf(te[2]) | ((unsigned)f2bf(to[2]) << 16);           \
    pk.w = (unsigned)f2bf(te[3]) | ((unsigned)f2bf(to[3]) << 16);           \
    *(uint4*)(bdst + (BUF) * 8192) = pk;                                    \
  }

#define COMPUTE(BUF)                                                        \
  {                                                                         \
    const char* pA = (const char*)As;                                       \
    const char* pB = (const char*)&Bs[BUF][0];                              \
    short8 a0[4], b0[4];                                                    \
    _Pragma("unroll")                                                       \
    for (int m = 0; m < 4; ++m) a0[m] = *(const short8*)(pA + offA[m]);     \
    _Pragma("unroll")                                                       \
    for (int n = 0; n < 4; ++n) b0[n] = *(const short8*)(pB + offB[n]);     \
    _Pragma("unroll")                                                       \
    for (int m = 0; m < 4; ++m)                                             \
      _Pragma("unroll")                                                     \
      for (int n = 0; n < 4; ++n)                                           \
        acc[m][n] = __builtin_amdgcn_mfma_f32_16x16x32_bf16(a0[m], b0[n], acc[m][n], 0, 0, 0); \
    _Pragma("unroll")                                                       \
    for (int m = 0; m < 4; ++m) a0[m] = *(const short8*)(pA + (offA[m] ^ 64)); \
    _Pragma("unroll")                                                       \
    for (int n = 0; n < 4; ++n) b0[n] = *(const short8*)(pB + (offB[n] ^ 64)); \
    _Pragma("unroll")                                                       \
    for (int m = 0; m < 4; ++m)                                             \
      _Pragma("unroll")                                                     \
      for (int n = 0; n < 4; ++n)                                           \
        acc[m][n] = __builtin_amdgcn_mfma_f32_16x16x32_bf16(a0[m], b0[n], acc[m][n], 0, 0, 0); \
  }

  // ---- prologue: A(0); B(0),B(1) in regs; publish B(0) ----
  ASTAGE(0)
  __builtin_amdgcn_sched_barrier(0);
  BLOADP(0, 0)
  BLOADP(1, 64)
  XW(0, 0)
  asm volatile("s_waitcnt vmcnt(2) lgkmcnt(0)" ::: "memory");  // A(0)+Bs[0] ready; B(1) may fly
  __builtin_amdgcn_sched_barrier(0);
  __builtin_amdgcn_s_barrier();
  __builtin_amdgcn_sched_barrier(0);

  // ---- steps 0..5: full pipeline ----
#define STEP_MID(KT)                                                        \
  COMPUTE((KT) & 1)                                                         \
  __builtin_amdgcn_sched_barrier(0);                                        \
  __builtin_amdgcn_s_barrier();        /* all waves done reading Bs[KT&1] */\
  __builtin_amdgcn_sched_barrier(0);                                        \
  ASTAGE(((KT) + 1) * 64)              /* overwrite own As rows */          \
  __builtin_amdgcn_sched_barrier(0);   /* keep A before B in vmcnt FIFO */  \
  BLOADP((KT) & 1, ((KT) + 2) * 64)                                         \
  XW(((KT) + 1) & 1, ((KT) + 1) & 1)                                        \
  asm volatile("s_waitcnt vmcnt(2) lgkmcnt(0)" ::: "memory");               \
  __builtin_amdgcn_sched_barrier(0);                                        \
  __builtin_amdgcn_s_barrier();                                             \
  __builtin_amdgcn_sched_barrier(0);

  STEP_MID(0)
  STEP_MID(1)
  STEP_MID(2)
  STEP_MID(3)
  STEP_MID(4)
  STEP_MID(5)

  // ---- step 6: stage A(7), publish B(7); no more B loads ----
  COMPUTE(0)
  __builtin_amdgcn_sched_barrier(0);
  __builtin_amdgcn_s_barrier();
  __builtin_amdgcn_sched_barrier(0);
  ASTAGE(7 * 64)
  XW(1, 1)
  asm volatile("s_waitcnt vmcnt(0) lgkmcnt(0)" ::: "memory");
  __builtin_amdgcn_sched_barrier(0);
  __builtin_amdgcn_s_barrier();
  __builtin_amdgcn_sched_barrier(0);

  // ---- step 7 ----
  COMPUTE(1)

#undef STEP_MID
#undef COMPUTE
#undef XW
#undef BLOADP
#undef ASTAGE

  // ---- column norms: red[w][cT] = ss (each lane owns a distinct col) ----
  __syncthreads();
  red[w][cT] = ss;
  __syncthreads();
  if (tid < BN) {
    float s = 0.f;
    #pragma unroll
    for (int r = 0; r < 8; ++r) s += red[r][tid];
    invn_s[tid] = (s > 0.f) ? rsqrtf(s) : 0.f;
  }
  __syncthreads();

  // ---- epilogue: scale by invn, clip, margin on label column ----
  float invc[4];
  #pragma unroll
  for (int n = 0; n < 4; ++n) invc[n] = invn_s[n * 16 + l15];

  #pragma unroll
  for (int m = 0; m < 4; ++m) {
    int grow0 = w * 64 + m * 16 + q * 4;
    #pragma unroll
    for (int n = 0; n < 4; ++n) {
      int gc = c0 + n * 16 + l15;
      if (gc >= C_SZ) continue;
      #pragma unroll
      for (int r = 0; r < 4; ++r) {
        int grow = grow0 + r;
        float v = acc[m][n][r] * invc[n];
        v = fminf(fmaxf(v, -1.f + EPS_F), 1.f - EPS_F);
        float res = v * S_CONST;
        if (gc == lab_s[grow]) {
          float th = acosf(v) + ga_s[grow];
          th = fminf(fmaxf(th, EPS_F), PI_F - EPS_F);
          res = (cosf(th) - gadd_s[grow]) * S_CONST;
        }
        out[(size_t)grow * C_SZ + gc] = res;
      }
    }
  }
}

// ---------------- launch ----------------
extern "C" void kernel_launch(void* const* d_in, const int* in_sizes, int n_in,
                              void* d_out, int out_size, void* d_ws, size_t ws_size,
                              hipStream_t stream) {
  const float* emb   = (const float*)d_in[0];
  const float* norms = (const float*)d_in[1];
  const int*   label = (const int*)d_in[2];
  const float* kmat  = (const float*)d_in[3];
  float* out = (float*)d_out;

  // ws layout: [0,2048) ga | [2048,4096) gadd | [4096, 4096+512K) Abf
  char* ws = (char*)d_ws;
  float* ga   = (float*)ws;
  float* gadd = (float*)(ws + 2048);
  unsigned short* abf = (unsigned short*)(ws + 4096);

  k_stats<<<1, 512, 0, stream>>>(norms, label, ga, gadd);
  k_cvtA<<<256, 256, 0, stream>>>(emb, abf);
  k_gemm_full<<<NBLK, 512, 0, stream>>>(abf, kmat, label, ga, gadd, out);
}

// Round 7
// 157.904 us; speedup vs baseline: 1.0478x; 1.0478x over previous
//
#include <hip/hip_runtime.h>
#include <hip/hip_bf16.h>
#include <cstdint>
#include <cstddef>
#include <math.h>

#define B_SZ 512
#define E_SZ 512
#define C_SZ 70722
#define PAD_C 70784          // 553 * 128
#define M_MARGIN 0.4f
#define H_CONST 0.333f
#define S_CONST 64.0f
#define EPS_F 1e-3f
#define PI_F 3.14159265358979323846f

typedef __attribute__((ext_vector_type(8))) short short8;
typedef __attribute__((ext_vector_type(4))) float f32x4;

// ---------------- helpers ----------------

__device__ __forceinline__ unsigned short f2bf(float x) {
  __hip_bfloat16 h = __float2bfloat16(x);
  unsigned short u;
  __builtin_memcpy(&u, &h, 2);
  return u;
}

__device__ __forceinline__ void gload_lds16(const void* g, void* l) {
  __builtin_amdgcn_global_load_lds(
      (const __attribute__((address_space(1))) unsigned int*)g,
      (__attribute__((address_space(3))) unsigned int*)l, 16, 0, 0);
}

// XOR swizzle (byte units, bits 4-6) for 128B-row LDS tiles
__device__ __forceinline__ int swzb(int rc) {
  return (((rc & 7) ^ ((rc >> 2) & 7)) << 4);
}

// ---------------- kernel 1: per-row margin stats ----------------
__global__ void k_stats(const float* __restrict__ norms, const int* __restrict__ label,
                        float* __restrict__ ga, float* __restrict__ gadd) {
  __shared__ float sn[B_SZ];
  __shared__ int lab[B_SZ];
  __shared__ float redA[8], redB[8];
  __shared__ float sh_std;

  int t = threadIdx.x;
  float v = norms[t];
  v = fminf(fmaxf(v, 1e-3f), 100.0f);
  sn[t] = v;
  lab[t] = label[t];

  float s1 = v, s2 = v * v;
  #pragma unroll
  for (int o = 32; o > 0; o >>= 1) {
    s1 += __shfl_down(s1, o);
    s2 += __shfl_down(s2, o);
  }
  if ((t & 63) == 0) { redA[t >> 6] = s1; redB[t >> 6] = s2; }
  __syncthreads();
  if (t == 0) {
    float a = 0.f, b = 0.f;
    #pragma unroll
    for (int i = 0; i < 8; ++i) { a += redA[i]; b += redB[i]; }
    float mean = a / (float)B_SZ;
    float var = (b - (float)B_SZ * mean * mean) / (float)(B_SZ - 1);
    sh_std = sqrtf(fmaxf(var, 0.f));
  }
  __syncthreads();
  float stdv = sh_std;

  int myl = lab[t];
  float s = 0.f, cnt = 0.f;
  for (int j = 0; j < B_SZ; ++j) {
    bool m = (lab[j] == myl);
    s += m ? sn[j] : 0.f;
    cnt += m ? 1.f : 0.f;
  }
  float gm = s / fmaxf(cnt, 1.f);
  float ms = (v - gm) / (stdv + EPS_F) * H_CONST;
  ms = fminf(fmaxf(ms, -1.f), 1.f);
  ga[t] = -M_MARGIN * ms;
  gadd[t] = M_MARGIN + M_MARGIN * ms;
}

// ---------------- kernel 2: emb fp32 -> bf16 ----------------
__global__ void k_cvtA(const float* __restrict__ emb, unsigned short* __restrict__ abf) {
  int i = (blockIdx.x * 256 + threadIdx.x) * 4;
  float4 f = *(const float4*)(emb + i);
  unsigned short u0 = f2bf(f.x), u1 = f2bf(f.y), u2 = f2bf(f.z), u3 = f2bf(f.w);
  unsigned long long pk = (unsigned long long)u0 | ((unsigned long long)u1 << 16) |
                          ((unsigned long long)u2 << 32) | ((unsigned long long)u3 << 48);
  *(unsigned long long*)(abf + i) = pk;
}

// ---------------- kernel 3: fused colnorm + transpose-convert ----------------
__global__ void k_prep(const float* __restrict__ K, float* __restrict__ invn,
                       unsigned short* __restrict__ BT) {
  __shared__ float T[64 * 64];        // [k][c^((k&7)<<2)]
  __shared__ float part[16][64];

  const int t = threadIdx.x;
  const int c0 = blockIdx.x * 64;
  const int cl = t & 15;
  const int kr = t >> 4;
  const int cq = t >> 2;
  const int kq = t & 3;
  const bool full = (c0 + 64 <= C_SZ);

  float ss0 = 0.f, ss1 = 0.f, ss2 = 0.f, ss3 = 0.f;

  for (int ch = 0; ch < 8; ++ch) {
    if (ch) __syncthreads();
    #pragma unroll
    for (int i = 0; i < 4; ++i) {
      int klo = kr + i * 16;
      int kg = ch * 64 + klo;
      float4 f;
      if (full) {
        f = *(const float4*)(K + (size_t)kg * C_SZ + c0 + cl * 4);
      } else {
        float* fp = (float*)&f;
        #pragma unroll
        for (int j = 0; j < 4; ++j) {
          int c = c0 + cl * 4 + j;
          fp[j] = (c < C_SZ) ? K[(size_t)kg * C_SZ + c] : 0.f;
        }
      }
      ss0 += f.x * f.x; ss1 += f.y * f.y; ss2 += f.z * f.z; ss3 += f.w * f.w;
      int swz = (klo & 7) << 2;
      *(float4*)&T[klo * 64 + ((cl * 4) ^ swz)] = f;
    }
    __syncthreads();
    #pragma unroll
    for (int sub = 0; sub < 2; ++sub) {
      int k8 = sub * 32 + kq * 8;
      short8 v;
      #pragma unroll
      for (int i = 0; i < 8; ++i) {
        v[i] = (short)f2bf(T[(k8 + i) * 64 + (cq ^ (i << 2))]);
      }
      *(short8*)(BT + ((size_t)(c0 + cq) << 9) + ch * 64 + k8) = v;
    }
  }

  __syncthreads();
  part[kr][cl * 4 + 0] = ss0;
  part[kr][cl * 4 + 1] = ss1;
  part[kr][cl * 4 + 2] = ss2;
  part[kr][cl * 4 + 3] = ss3;
  __syncthreads();
  if (t < 64) {
    int c = c0 + t;
    float s = 0.f;
    #pragma unroll
    for (int r = 0; r < 16; ++r) s += part[r][t];
    invn[c] = (c < C_SZ) ? rsqrtf(s) : 0.f;
  }
}

// ---------------- kernel 4: GEMM + LDS-transposed vector-store epilogue ----------------
__launch_bounds__(256)
__global__ void k_gemm_fast(const unsigned short* __restrict__ Abf,  // [512][512]
                            const unsigned short* __restrict__ BT,   // [PAD_C][512]
                            const float* __restrict__ invn,          // [PAD_C]
                            const int* __restrict__ label,
                            const float* __restrict__ ga,
                            const float* __restrict__ gadd,
                            float* __restrict__ out) {
  // union: K-loop uses As[16KB]+Bs[16KB]; epilogue reuses as cep[64][132] f32 (33.8KB)
  __shared__ __align__(16) unsigned char smem[64 * 132 * 4];
  unsigned short* As = (unsigned short*)smem;            // [0, 16384)
  unsigned short* Bs = (unsigned short*)(smem + 16384);  // [16384, 32768)
  float* cep = (float*)smem;                             // [0, 33792)
  __shared__ int lab_s[128];
  __shared__ float ga_s[128], gadd_s[128];

  const int tid = threadIdx.x;
  const int nwg = gridDim.x;
  int bid = blockIdx.x;

  int q8 = nwg >> 3, r8 = nwg & 7;
  int xcd = bid & 7, lb = bid >> 3;
  int wg = (xcd < r8 ? xcd * (q8 + 1) : r8 * (q8 + 1) + (xcd - r8) * q8) + lb;

  const int mt = wg & 3;
  const int nt = wg >> 2;
  const int row0 = mt << 7;
  const int col0 = nt << 7;

  if (tid < 128) {
    int gr = row0 + tid;
    lab_s[tid] = label[gr];
    ga_s[tid] = ga[gr];
    gadd_s[tid] = gadd[gr];
  }

  const int wid = tid >> 6, lane = tid & 63;
  const int wr = wid >> 1, wc = wid & 1;
  const int q = lane >> 4;
  const int l15 = lane & 15;

  f32x4 acc[4][4];
  #pragma unroll
  for (int m = 0; m < 4; ++m)
    #pragma unroll
    for (int n = 0; n < 4; ++n)
      acc[m][n] = f32x4{0.f, 0.f, 0.f, 0.f};

  const int rsub = lane >> 3;
  const int lchunk = lane & 7;

  for (int kt = 0; kt < 8; ++kt) {
    const int kb = kt * 64;
    if (kt) __syncthreads();

    #pragma unroll
    for (int rr = 0; rr < 4; ++rr) {
      int rowblk = wid * 32 + rr * 8;            // wave-uniform LDS base
      int r = rowblk + rsub;
      int s = lchunk ^ ((r & 7) ^ ((r >> 2) & 7));
      gload_lds16(Abf + (size_t)(row0 + r) * 512 + kb + s * 8,
                  (char*)As + rowblk * 128);
      gload_lds16(BT + (size_t)(col0 + r) * 512 + kb + s * 8,
                  (char*)Bs + rowblk * 128);
    }

    __syncthreads();

    #pragma unroll
    for (int ks = 0; ks < 2; ++ks) {
      short8 a[4], b[4];
      #pragma unroll
      for (int m = 0; m < 4; ++m) {
        int row = wr * 64 + m * 16 + l15;
        int off = (row * 128 + ks * 64 + q * 16) ^ swzb(row);
        a[m] = *(const short8*)((const char*)As + off);
      }
      #pragma unroll
      for (int n = 0; n < 4; ++n) {
        int c = wc * 64 + n * 16 + l15;
        int off = (c * 128 + ks * 64 + q * 16) ^ swzb(c);
        b[n] = *(const short8*)((const char*)Bs + off);
      }
      #pragma unroll
      for (int m = 0; m < 4; ++m)
        #pragma unroll
        for (int n = 0; n < 4; ++n)
          acc[m][n] = __builtin_amdgcn_mfma_f32_16x16x32_bf16(a[m], b[n], acc[m][n], 0, 0, 0);
    }
  }

  // ---- epilogue: per-element math -> LDS transpose slice -> float4 NT stores ----
  float invc[4];
  #pragma unroll
  for (int n = 0; n < 4; ++n)
    invc[n] = invn[col0 + wc * 64 + n * 16 + l15];

  const int rloc = tid >> 5;       // 0..7
  const int qd = tid & 31;         // col quad 0..31

  #pragma unroll
  for (int p = 0; p < 2; ++p) {
    __syncthreads();               // previous use of smem done
    if (wr == p) {
      #pragma unroll
      for (int m = 0; m < 4; ++m) {
        #pragma unroll
        for (int n = 0; n < 4; ++n) {
          int cl = wc * 64 + n * 16 + l15;   // 0..127
          int gc = col0 + cl;
          float iv = invc[n];
          #pragma unroll
          for (int r = 0; r < 4; ++r) {
            int rl = m * 16 + q * 4 + r;     // local row 0..63
            float v = acc[m][n][r] * iv;
            v = fminf(fmaxf(v, -1.f + EPS_F), 1.f - EPS_F);
            float res = v * S_CONST;
            if (gc == lab_s[p * 64 + rl]) {
              float th = acosf(v) + ga_s[p * 64 + rl];
              th = fminf(fmaxf(th, EPS_F), PI_F - EPS_F);
              res = (cosf(th) - gadd_s[p * 64 + rl]) * S_CONST;
            }
            cep[rl * 132 + cl] = res;
          }
        }
      }
    }
    __syncthreads();
    // drain: 512B contiguous per 32 lanes, nontemporal f32x4
    #pragma unroll
    for (int it = 0; it < 8; ++it) {
      int row = rloc + it * 8;               // 0..63
      f32x4 v = *(const f32x4*)(cep + row * 132 + qd * 4);
      int grow = row0 + p * 64 + row;
      int gc0 = col0 + qd * 4;
      float* dst = out + (size_t)grow * C_SZ + gc0;
      if (gc0 + 4 <= C_SZ) {
        __builtin_nontemporal_store(v, (f32x4*)dst);
      } else {
        #pragma unroll
        for (int j = 0; j < 4; ++j)
          if (gc0 + j < C_SZ) __builtin_nontemporal_store(v[j], dst + j);
      }
    }
  }
}

// ================= fallback path (round-1, known-good) =================

__global__ void k_colnorm(const float* __restrict__ K, float* __restrict__ inv) {
  __shared__ float part[4][64];
  int cl = threadIdx.x & 63;
  int rq = threadIdx.x >> 6;
  int c = blockIdx.x * 64 + cl;
  float s = 0.f;
  if (c < C_SZ) {
    const float* p = K + (size_t)rq * 128 * C_SZ + c;
    #pragma unroll 8
    for (int r = 0; r < 128; ++r) {
      float x = p[(size_t)r * C_SZ];
      s += x * x;
    }
  }
  part[rq][cl] = s;
  __syncthreads();
  if (threadIdx.x < 64) {
    int c2 = blockIdx.x * 64 + threadIdx.x;
    if (c2 < C_SZ) {
      float tt = part[0][threadIdx.x] + part[1][threadIdx.x] +
                 part[2][threadIdx.x] + part[3][threadIdx.x];
      inv[c2] = rsqrtf(tt);
    } else if (c2 < PAD_C) {
      inv[c2] = 0.f;
    }
  }
}

__launch_bounds__(256)
__global__ void k_gemm_fb(const unsigned short* __restrict__ Abf,
                          const float* __restrict__ Kmat,
                          const float* __restrict__ invn,
                          const int* __restrict__ label,
                          const float* __restrict__ ga,
                          const float* __restrict__ gadd,
                          float* __restrict__ out) {
  __shared__ __align__(16) unsigned short As[128 * 64];
  __shared__ __align__(16) unsigned short Bs[128 * 64];
  __shared__ int lab_s[128];
  __shared__ float ga_s[128], gadd_s[128];

  const int tid = threadIdx.x;
  const int nwg = gridDim.x;
  int bid = blockIdx.x;
  int q = nwg >> 3, r8 = nwg & 7;
  int xcd = bid & 7, lb = bid >> 3;
  int wg = (xcd < r8 ? xcd * (q + 1) : r8 * (q + 1) + (xcd - r8) * q) + lb;
  const int mt = wg & 3;
  const int nt = wg >> 2;
  const int row0 = mt << 7;
  const int col0 = nt << 7;

  if (tid < 128) {
    int gr = row0 + tid;
    lab_s[tid] = label[gr];
    ga_s[tid] = ga[gr];
    gadd_s[tid] = gadd[gr];
  }

  const int wid = tid >> 6, lane = tid & 63;
  const int wr = wid >> 1, wc = wid & 1;
  const int cc = tid & 31;
  const int kq = tid >> 5;
  const bool edge = (col0 + 128 > C_SZ);
  float4 inv4 = *(const float4*)(invn + col0 + cc * 4);

  f32x4 acc[4][4];
  #pragma unroll
  for (int m = 0; m < 4; ++m)
    #pragma unroll
    for (int n = 0; n < 4; ++n)
      acc[m][n] = f32x4{0.f, 0.f, 0.f, 0.f};

  const float* Bg = Kmat + col0;

  for (int kt = 0; kt < 8; ++kt) {
    const int kb = kt * 64;
    if (kt) __syncthreads();

    #pragma unroll
    for (int rr = 0; rr < 4; ++rr) {
      int rowblk = wid * 32 + rr * 8;
      int r = rowblk + (lane >> 3);
      int s = (lane & 7) ^ ((r & 7) ^ ((r >> 2) & 7));
      gload_lds16(Abf + (size_t)(row0 + r) * 512 + kb + s * 8, (char*)As + rowblk * 128);
    }

    #pragma unroll
    for (int i = 0; i < 4; ++i) {
      int k = (kq + i * 8) * 2;
      const float* g0 = Bg + (size_t)(kb + k) * C_SZ + cc * 4;
      const float* g1 = g0 + C_SZ;
      float x0[4], x1[4];
      if (!edge) {
        float4 f0 = *(const float4*)g0;
        float4 f1 = *(const float4*)g1;
        x0[0]=f0.x; x0[1]=f0.y; x0[2]=f0.z; x0[3]=f0.w;
        x1[0]=f1.x; x1[1]=f1.y; x1[2]=f1.z; x1[3]=f1.w;
      } else {
        #pragma unroll
        for (int j = 0; j < 4; ++j) {
          int gc = col0 + cc * 4 + j;
          x0[j] = (gc < C_SZ) ? g0[j] : 0.f;
          x1[j] = (gc < C_SZ) ? g1[j] : 0.f;
        }
      }
      #pragma unroll
      for (int j = 0; j < 4; ++j) {
        int c = cc * 4 + j;
        float iv = ((const float*)&inv4)[j];
        unsigned int pk = ((unsigned int)f2bf(x1[j] * iv) << 16) | (unsigned int)f2bf(x0[j] * iv);
        int byte = (c * 128 + k * 2) ^ swzb(c);
        *(unsigned int*)((char*)Bs + byte) = pk;
      }
    }

    __syncthreads();

    #pragma unroll
    for (int ks = 0; ks < 2; ++ks) {
      short8 a[4], b[4];
      #pragma unroll
      for (int m = 0; m < 4; ++m) {
        int row = wr * 64 + m * 16 + (lane & 15);
        int off = (row * 128 + ks * 64 + (lane >> 4) * 16) ^ swzb(row);
        a[m] = *(const short8*)((const char*)As + off);
      }
      #pragma unroll
      for (int n = 0; n < 4; ++n) {
        int c = wc * 64 + n * 16 + (lane & 15);
        int off = (c * 128 + ks * 64 + (lane >> 4) * 16) ^ swzb(c);
        b[n] = *(const short8*)((const char*)Bs + off);
      }
      #pragma unroll
      for (int m = 0; m < 4; ++m)
        #pragma unroll
        for (int n = 0; n < 4; ++n)
          acc[m][n] = __builtin_amdgcn_mfma_f32_16x16x32_bf16(a[m], b[n], acc[m][n], 0, 0, 0);
    }
  }

  #pragma unroll
  for (int m = 0; m < 4; ++m) {
    int rl0 = wr * 64 + m * 16 + ((lane >> 4) << 2);
    #pragma unroll
    for (int n = 0; n < 4; ++n) {
      int cl = wc * 64 + n * 16 + (lane & 15);
      int gc = col0 + cl;
      if (gc >= C_SZ) continue;
      #pragma unroll
      for (int r = 0; r < 4; ++r) {
        int rl = rl0 + r;
        float v = acc[m][n][r];
        v = fminf(fmaxf(v, -1.f + EPS_F), 1.f - EPS_F);
        float res = v * S_CONST;
        if (gc == lab_s[rl]) {
          float th = acosf(v) + ga_s[rl];
          th = fminf(fmaxf(th, EPS_F), PI_F - EPS_F);
          res = (cosf(th) - gadd_s[rl]) * S_CONST;
        }
        out[(size_t)(row0 + rl) * C_SZ + gc] = res;
      }
    }
  }
}

// ---------------- launch ----------------
extern "C" void kernel_launch(void* const* d_in, const int* in_sizes, int n_in,
                              void* d_out, int out_size, void* d_ws, size_t ws_size,
                              hipStream_t stream) {
  const float* emb   = (const float*)d_in[0];
  const float* norms = (const float*)d_in[1];
  const int*   label = (const int*)d_in[2];
  const float* kmat  = (const float*)d_in[3];
  float* out = (float*)d_out;

  // fast-path ws layout:
  //   [0, 283136)          invn  float[PAD_C]
  //   [283136, 285184)     ga    float[512]
  //   [285184, 287232)     gadd  float[512]
  //   [287232, 811520)     Abf   bf16[512*512]
  //   [811520, 73294336)   BT    bf16[PAD_C][512]
  const size_t NEED_FAST = 73294336;
  char* ws = (char*)d_ws;
  float* invn = (float*)ws;
  float* ga   = (float*)(ws + 283136);
  float* gadd = (float*)(ws + 285184);
  unsigned short* abf = (unsigned short*)(ws + 287232);
  unsigned short* bt  = (unsigned short*)(ws + 811520);

  k_stats<<<1, 512, 0, stream>>>(norms, label, ga, gadd);
  k_cvtA<<<256, 256, 0, stream>>>(emb, abf);

  if (ws_size >= NEED_FAST) {
    k_prep<<<1106, 256, 0, stream>>>(kmat, invn, bt);
    k_gemm_fast<<<2212, 256, 0, stream>>>(abf, bt, invn, label, ga, gadd, out);
  } else {
    k_colnorm<<<1106, 256, 0, stream>>>(kmat, invn);
    k_gemm_fb<<<2212, 256, 0, stream>>>(abf, kmat, invn, label, ga, gadd, out);
  }
}